// Round 5
// baseline (99.894 us; speedup 1.0000x reference)
//
#include <hip/hip_runtime.h>
#include <hip/hip_bf16.h>
#include <math.h>

// Sizes (fixed by the problem)
#define B 8
#define MEM_LEN 512
#define DEC_LEN 32
#define MEM_H 512
#define DEC_H 512
#define HDIM 1024
#define M1 (MEM_LEN + 1)   // 513
#define MF_ROWS 4224       // 33 * 128 : padded rows for pm GEMM tiles
#define PM_ROWS (B * M1)   // 4104

// Finite -inf stand-in (exact -inf makes |ref-out| = NaN in the harness check).
#define NEG_BIG (-1e30f)
// 2*log2(e): tanh(x) = 1 - 2*rcp(1 + exp2(C2*x)); C2 is pre-folded into pm/pd.
#define C2F 2.885390081777927f

#if __has_builtin(__builtin_amdgcn_exp2f)
#define EXP2(x) __builtin_amdgcn_exp2f(x)
#else
#define EXP2(x) exp2f(x)
#endif
#define RCP(x) __builtin_amdgcn_rcpf(x)

typedef __bf16 bfv8 __attribute__((ext_vector_type(8)));
typedef float  f4   __attribute__((ext_vector_type(4)));
typedef float  f8   __attribute__((ext_vector_type(8)));

// ---------------------------------------------------------------------------
// Kernel 1: convert all GEMM operands to bf16 (and assemble mem_full+zero pad).
// One thread = 8 elements. Regions: [mf | dec | W_mem | W_dec]
// ---------------------------------------------------------------------------
#define N_MF  (MF_ROWS * 512 / 8)       // 270336
#define N_DEC (256 * 512 / 8)           // 16384
#define N_W   (1024 * 512 / 8)          // 65536
#define N_CVT (N_MF + N_DEC + 2 * N_W)  // 417792 = 1632*256

__global__ __launch_bounds__(256) void convert_all(
        const float* __restrict__ mem, const float* __restrict__ term,
        const float* __restrict__ dec_hid,
        const float* __restrict__ W_mem, const float* __restrict__ W_dec,
        __bf16* __restrict__ mfb, __bf16* __restrict__ decb,
        __bf16* __restrict__ wmb, __bf16* __restrict__ wdb) {
    int idx = blockIdx.x * 256 + threadIdx.x;
    float4 v0 = make_float4(0.f, 0.f, 0.f, 0.f), v1 = v0;
    __bf16* dst;
    if (idx < N_MF) {
        int row = idx >> 6;          // 64 chunks of 8 per 512-wide row
        int c8  = idx & 63;
        dst = mfb + (size_t)idx * 8;
        if (row < PM_ROWS) {
            int b = row / M1, m = row - b * M1;
            const float* src = (m == 0) ? (term + c8 * 8)
                                        : (mem + ((size_t)(b * MEM_LEN + m - 1)) * 512 + c8 * 8);
            v0 = ((const float4*)src)[0];
            v1 = ((const float4*)src)[1];
        } // else rows >= 4104 stay zero (GEMM pad)
    } else if (idx < N_MF + N_DEC) {
        int j = idx - N_MF;
        dst = decb + (size_t)j * 8;
        v0 = ((const float4*)dec_hid)[j * 2];
        v1 = ((const float4*)dec_hid)[j * 2 + 1];
    } else if (idx < N_MF + N_DEC + N_W) {
        int j = idx - N_MF - N_DEC;
        dst = wmb + (size_t)j * 8;
        v0 = ((const float4*)W_mem)[j * 2];
        v1 = ((const float4*)W_mem)[j * 2 + 1];
    } else {
        int j = idx - N_MF - N_DEC - N_W;
        dst = wdb + (size_t)j * 8;
        v0 = ((const float4*)W_dec)[j * 2];
        v1 = ((const float4*)W_dec)[j * 2 + 1];
    }
    bfv8 o;
    o[0] = (__bf16)v0.x; o[1] = (__bf16)v0.y; o[2] = (__bf16)v0.z; o[3] = (__bf16)v0.w;
    o[4] = (__bf16)v1.x; o[5] = (__bf16)v1.y; o[6] = (__bf16)v1.z; o[7] = (__bf16)v1.w;
    *(bfv8*)dst = o;
}

// ---------------------------------------------------------------------------
// Kernel 2: bf16 MFMA GEMM  C = C2 * (A[Mpad][512] * W[1024][512]^T + bias)
// Block = 128x128 tile, 4 waves (2x2), each wave a 64x64 sub-tile (4x4 MFMA
// frags): 16 MFMA per 8 loads per k-step -> MFMA:load = 2:1, 16 independent
// acc chains. Everything L2-resident; unroll keeps >=16 loads in flight.
// Layouts (HW-verified m89/m91): A/B frag: lane l -> row/col (l&15),
// k = (l>>4)*8 + j. C/D: col = l&15, row = (l>>4)*4 + reg.
// C2 folded here so score3's exp2 arg is a plain add.
// ---------------------------------------------------------------------------
template <typename OutT>
__global__ __launch_bounds__(256) void gemm_mfma3(
        const __bf16* __restrict__ A, const __bf16* __restrict__ Wb,
        const float* __restrict__ bias, OutT* __restrict__ C) {
    int w = threadIdx.x >> 6, l = threadIdx.x & 63;
    int m0 = blockIdx.x * 128 + (w >> 1) * 64;
    int n0 = blockIdx.y * 128 + (w & 1) * 64;
    int lr = l & 15;
    int lk = (l >> 4) * 8;
    const __bf16* Ab = A  + (size_t)(m0 + lr) * 512 + lk;
    const __bf16* Bb = Wb + (size_t)(n0 + lr) * 512 + lk;

    f4 acc[4][4] = {};
    #pragma unroll 4
    for (int k0 = 0; k0 < 512; k0 += 32) {
        bfv8 a[4], bb[4];
        #pragma unroll
        for (int i = 0; i < 4; ++i) a[i]  = *(const bfv8*)(Ab + (size_t)i * 16 * 512 + k0);
        #pragma unroll
        for (int j = 0; j < 4; ++j) bb[j] = *(const bfv8*)(Bb + (size_t)j * 16 * 512 + k0);
        #pragma unroll
        for (int i = 0; i < 4; ++i)
            #pragma unroll
            for (int j = 0; j < 4; ++j)
                acc[i][j] = __builtin_amdgcn_mfma_f32_16x16x32_bf16(a[i], bb[j], acc[i][j], 0, 0, 0);
    }

    int crow = (l >> 4) * 4;
    int ccol = l & 15;
    #pragma unroll
    for (int j = 0; j < 4; ++j) {
        int col = n0 + j * 16 + ccol;
        float bv = bias[col];
        #pragma unroll
        for (int i = 0; i < 4; ++i) {
            #pragma unroll
            for (int r = 0; r < 4; ++r) {
                int row = m0 + i * 16 + crow + r;
                C[(size_t)row * HDIM + col] = (OutT)((acc[i][j][r] + bv) * C2F);
            }
        }
    }
}

// ---------------------------------------------------------------------------
// Kernel 3: score[b,d,m] = sum_h w[h] * tanh(pm[b,m,h] + pd[b,d,h])  (+masks)
//   = SumW - sum_h 2*w[h]*rcp(1 + exp2(pm_s + pd_s))   (pm_s,pd_s pre-scaled)
// Grid: b(8) x dgroup(8, 4 d's each) x mchunk(17, 32 rows). b = bid&7 -> XCD.
// Block 256 thr = 4 waves; wave w rows mbase..mbase+7; lane covers 16 h
// (l*8 in each 512-half). 8 independent fma chains (4 d x 2 halves).
// Writes raw scores (masked -> NEG_BIG) to sc; softmax separate.
// ---------------------------------------------------------------------------
__global__ __launch_bounds__(256) void score3(
        const __bf16* __restrict__ pm, const float* __restrict__ pd,
        const float* __restrict__ w_score,
        const unsigned char* __restrict__ mem_mask,
        const unsigned char* __restrict__ dec_mask,
        const unsigned char* __restrict__ dup_mask,
        float* __restrict__ sc) {
    int bid = blockIdx.x;
    int b    = bid & 7;
    int rest = bid >> 3;
    int dg   = rest & 7;                   // 8 groups of 4 d
    int mc   = rest >> 3;                  // 0..16
    int t = threadIdx.x, w = t >> 6, l = t & 63;
    int bd0 = b * DEC_LEN + dg * 4;

    // per-lane state: pre-scaled pd rows (4 d x 2 halves) + 2*w + sum(w)
    f8 pdv[4][2], w22[2];
    float sumw_l = 0.f;
    #pragma unroll
    for (int half = 0; half < 2; ++half) {
        int h = half * 512 + l * 8;
        f8 wv = *(const f8*)(w_score + h);
        #pragma unroll
        for (int d = 0; d < 4; ++d)
            pdv[d][half] = *(const f8*)(pd + (size_t)(bd0 + d) * HDIM + h);
        #pragma unroll
        for (int j = 0; j < 8; ++j) {
            sumw_l += wv[j];
            w22[half][j] = wv[j] * 2.f;
        }
    }
    #pragma unroll
    for (int off = 32; off; off >>= 1) sumw_l += __shfl_xor(sumw_l, off, 64);
    float sumw_all = sumw_l;               // sum_h w[h], identical in all lanes

    bool dm[4];
    #pragma unroll
    for (int d = 0; d < 4; ++d) dm[d] = dec_mask[bd0 + d] != 0;
    const unsigned char* dup0 = dup_mask + (size_t)bd0 * M1;

    int mbase = mc * 32 + w * 8;
    for (int i = 0; i < 8; ++i) {
        int m = mbase + i;
        if (m >= M1) break;                // wave-uniform
        bool memm = (m > 0) && (mem_mask[b * MEM_LEN + m - 1] != 0);
        float s[4];
        if (memm) {
            #pragma unroll
            for (int d = 0; d < 4; ++d) s[d] = NEG_BIG;
        } else {
            const __bf16* pmr = pm + ((size_t)(b * M1 + m)) * HDIM + l * 8;
            bfv8 p0 = *(const bfv8*)(pmr);
            bfv8 p1 = *(const bfv8*)(pmr + 512);
            float ac[4][2] = {};
            #pragma unroll
            for (int j = 0; j < 8; ++j) {
                float pf = (float)p0[j];
                float pg = (float)p1[j];
                #pragma unroll
                for (int d = 0; d < 4; ++d) {
                    float e0 = EXP2(pf + pdv[d][0][j]);
                    ac[d][0] = fmaf(w22[0][j], RCP(e0 + 1.f), ac[d][0]);
                    float e1 = EXP2(pg + pdv[d][1][j]);
                    ac[d][1] = fmaf(w22[1][j], RCP(e1 + 1.f), ac[d][1]);
                }
            }
            float a0 = ac[0][0] + ac[0][1];
            float a1 = ac[1][0] + ac[1][1];
            float a2 = ac[2][0] + ac[2][1];
            float a3 = ac[3][0] + ac[3][1];
            #pragma unroll
            for (int off = 32; off; off >>= 1) {
                a0 += __shfl_xor(a0, off, 64);
                a1 += __shfl_xor(a1, off, 64);
                a2 += __shfl_xor(a2, off, 64);
                a3 += __shfl_xor(a3, off, 64);
            }
            s[0] = sumw_all - a0;
            s[1] = sumw_all - a1;
            s[2] = sumw_all - a2;
            s[3] = sumw_all - a3;
            #pragma unroll
            for (int d = 0; d < 4; ++d)
                if (!dm[d] && dup0[(size_t)d * M1 + m]) s[d] = NEG_BIG;
        }
        if (l == 0) {
            #pragma unroll
            for (int d = 0; d < 4; ++d)
                sc[(size_t)(bd0 + d) * M1 + m] = s[d];
        }
    }
}

// ---------------------------------------------------------------------------
// Kernel 4: row-wise log_softmax over 513 entries. One block per (b,d).
// ---------------------------------------------------------------------------
__global__ __launch_bounds__(512) void softmax_k(const float* __restrict__ sc,
                                                 float* __restrict__ out) {
    __shared__ float red[512];
    int bd = blockIdx.x, t = threadIdx.x;
    const float* row = sc + (size_t)bd * M1;
    float v = row[t];
    float v512 = row[512];
    float lm = (t == 0) ? fmaxf(v, v512) : v;
    red[t] = lm;
    __syncthreads();
    for (int s = 256; s > 0; s >>= 1) {
        if (t < s) red[t] = fmaxf(red[t], red[t + s]);
        __syncthreads();
    }
    float mx = red[0];
    __syncthreads();
    float le = __expf(v - mx);             // exp(NEG_BIG - mx) == 0 exactly
    if (t == 0) le += __expf(v512 - mx);
    red[t] = le;
    __syncthreads();
    for (int s = 256; s > 0; s >>= 1) {
        if (t < s) red[t] += red[t + s];
        __syncthreads();
    }
    float lse = mx + __logf(red[0]);
    float* orow = out + (size_t)bd * M1;
    orow[t] = v - lse;
    if (t == 0) orow[512] = v512 - lse;
}

// ---------------------------------------------------------------------------
extern "C" void kernel_launch(void* const* d_in, const int* in_sizes, int n_in,
                              void* d_out, int out_size, void* d_ws, size_t ws_size,
                              hipStream_t stream) {
    const float* mem      = (const float*)d_in[0];
    const float* dec_hid  = (const float*)d_in[1];
    const unsigned char* mem_mask = (const unsigned char*)d_in[2];
    const unsigned char* dec_mask = (const unsigned char*)d_in[3];
    const unsigned char* dup_mask = (const unsigned char*)d_in[4];
    const float* term     = (const float*)d_in[5];
    const float* W_mem    = (const float*)d_in[6];
    const float* b_mem    = (const float*)d_in[7];
    const float* W_dec    = (const float*)d_in[8];
    const float* b_dec    = (const float*)d_in[9];
    const float* w_score  = (const float*)d_in[10];
    // d_in[11] = b_score : unused (log_softmax is shift-invariant)

    float* out = (float*)d_out;
    char* ws = (char*)d_ws;
    __bf16* mfb  = (__bf16*)ws;                              // 4224*512*2  = 4,325,376
    __bf16* decb = mfb + (size_t)MF_ROWS * 512;              //  256*512*2  =   262,144
    __bf16* wmb  = decb + (size_t)256 * 512;                 // 1024*512*2  = 1,048,576
    __bf16* wdb  = wmb + (size_t)1024 * 512;                 // 1024*512*2  = 1,048,576
    __bf16* pmb  = wdb + (size_t)1024 * 512;                 // 4224*1024*2 = 8,650,752
    float*  pd   = (float*)(pmb + (size_t)MF_ROWS * HDIM);   //  256*1024*4 = 1,048,576
    float*  sc   = pd + (size_t)256 * HDIM;                  //  256*513*4  =   525,312

    convert_all<<<N_CVT / 256, 256, 0, stream>>>(mem, term, dec_hid, W_mem, W_dec,
                                                 mfb, decb, wmb, wdb);
    gemm_mfma3<__bf16><<<dim3(33, 8), 256, 0, stream>>>(mfb, wmb, b_mem, pmb);
    gemm_mfma3<float><<<dim3(2, 8), 256, 0, stream>>>(decb, wdb, b_dec, pd);
    score3<<<8 * 8 * 17, 256, 0, stream>>>(pmb, pd, w_score,
                                           mem_mask, dec_mask, dup_mask, sc);
    softmax_k<<<B * DEC_LEN, 512, 0, stream>>>(sc, out);
}